// Round 1
// baseline (333.388 us; speedup 1.0000x reference)
//
#include <hip/hip_runtime.h>

#define S_LEN 2048
#define N_B 2
#define N_H 16
#define N_KVH 4
#define HD 128
#define LDQ 2048   // N_H*HD
#define LDKV 512   // N_KVH*HD

typedef __bf16 bf16x8 __attribute__((ext_vector_type(8)));
typedef float f32x4 __attribute__((ext_vector_type(4)));

__device__ __forceinline__ float bf2f(unsigned short u){
  unsigned int x = ((unsigned int)u) << 16; float f;
  __builtin_memcpy(&f, &x, 4); return f;
}
__device__ __forceinline__ unsigned short f2bf(float f){
  unsigned int x; __builtin_memcpy(&x, &f, 4);
  unsigned int r = x + 0x7fff + ((x >> 16) & 1);
  return (unsigned short)(r >> 16);
}
__device__ __forceinline__ void gload16(const void* g, void* l){
  __builtin_amdgcn_global_load_lds((const __attribute__((address_space(1))) void*)g,
                                   (__attribute__((address_space(3))) void*)l, 16, 0, 0);
}
__device__ __forceinline__ float red16max(float v){
  v = fmaxf(v, __shfl_xor(v, 1)); v = fmaxf(v, __shfl_xor(v, 2));
  v = fmaxf(v, __shfl_xor(v, 4)); v = fmaxf(v, __shfl_xor(v, 8));
  return v;
}
__device__ __forceinline__ float red16sum(float v){
  v += __shfl_xor(v, 1); v += __shfl_xor(v, 2);
  v += __shfl_xor(v, 4); v += __shfl_xor(v, 8);
  return v;
}

// ---------------- cast fp32 -> bf16, 8 elems/thread ----------------
__global__ void cast_bf16(const float* __restrict__ in, unsigned short* __restrict__ out, int n8){
  int i = blockIdx.x * 256 + threadIdx.x;
  if (i >= n8) return;
  const float4* p = (const float4*)in + (size_t)i * 2;
  float4 a = p[0], b = p[1];
  uint4 o;
  o.x = (unsigned)f2bf(a.x) | ((unsigned)f2bf(a.y) << 16);
  o.y = (unsigned)f2bf(a.z) | ((unsigned)f2bf(a.w) << 16);
  o.z = (unsigned)f2bf(b.x) | ((unsigned)f2bf(b.y) << 16);
  o.w = (unsigned)f2bf(b.z) | ((unsigned)f2bf(b.w) << 16);
  ((uint4*)out)[i] = o;
}

// ---------------- RoPE in-place on bf16 buffer ----------------
// X: [tokens, 1<<ld_log2] bf16, head dim 128, fc: [S,64,2,2] fp32
__global__ void rope_kernel(unsigned short* __restrict__ X, const float* __restrict__ FC,
                            int ld_log2, int n8){
  int i = blockIdx.x * 256 + threadIdx.x;
  if (i >= n8) return;
  int idx = i * 8;
  int col = idx & ((1 << ld_log2) - 1);
  int token = idx >> ld_log2;
  int s = token & (S_LEN - 1);
  int d = col & (HD - 1);
  uint4 v = *(const uint4*)(X + idx);
  unsigned short* pv = (unsigned short*)&v;
  const float4* f4 = (const float4*)FC + ((size_t)s * 64 + (d >> 1));
  uint4 ov; unsigned short* po = (unsigned short*)&ov;
#pragma unroll
  for (int p = 0; p < 4; p++){
    float4 f = f4[p];
    float e = bf2f(pv[2*p]), o = bf2f(pv[2*p+1]);
    po[2*p]   = f2bf(f.x * e + f.y * o);
    po[2*p+1] = f2bf(f.z * e + f.w * o);
  }
  *(uint4*)(X + idx) = ov;
}

// ---------------- transpose V [B*S,512] -> Vt [B*4*128, S] ----------------
__global__ void transpose_v(const unsigned short* __restrict__ V, unsigned short* __restrict__ Vt){
  __shared__ unsigned short tile[32][33];
  int t = threadIdx.x;
  int s0 = blockIdx.x * 32;   // token tile
  int c0 = blockIdx.y * 32;   // col tile within 512
  int r = t >> 3, cg = (t & 7) * 4;
  uint2 in2 = *(const uint2*)(V + (size_t)(s0 + r) * LDKV + c0 + cg);
  unsigned short* pi = (unsigned short*)&in2;
  tile[r][cg+0] = pi[0]; tile[r][cg+1] = pi[1]; tile[r][cg+2] = pi[2]; tile[r][cg+3] = pi[3];
  __syncthreads();
  int b = s0 >> 11, sl = s0 & (S_LEN - 1);
  int kvh = c0 >> 7, dd0 = c0 & (HD - 1);
  int dd = t >> 3, sg = (t & 7) * 4;
  uint2 o2; unsigned short* po = (unsigned short*)&o2;
  po[0] = tile[sg+0][dd]; po[1] = tile[sg+1][dd]; po[2] = tile[sg+2][dd]; po[3] = tile[sg+3][dd];
  *(uint2*)(Vt + (size_t)((b * N_KVH + kvh) * HD + dd0 + dd) * S_LEN + sl + sg) = o2;
}

// ---------------- NT GEMM: C[M,N] = A[M,K] * Bm[N,K]^T, bf16 in, fp32 acc ----------------
__device__ __forceinline__ void storeC(float* C, size_t idx, float v){ C[idx] = v; }
__device__ __forceinline__ void storeC(unsigned short* C, size_t idx, float v){ C[idx] = f2bf(v); }

template <typename OutT>
__global__ __launch_bounds__(256, 2) void gemm_nt(const unsigned short* __restrict__ A,
                                                  const unsigned short* __restrict__ Bm,
                                                  OutT* __restrict__ C,
                                                  int M, int N, int K, int nbn){
  extern __shared__ char smem[];           // sA 16KB | sB 16KB
  char* sA = smem; char* sB = smem + 16384;
  int bid = blockIdx.x;
  int bn = bid % nbn, bm = bid / nbn;
  int row0 = bm * 128, col0 = bn * 128;
  int t = threadIdx.x; int w = t >> 6, l = t & 63;
  int lr = l & 15, lg = l >> 4;
  // staging coords: tile [128][64], per inst: 32 rows; XOR pre-swizzle on SOURCE col
  int srow = t >> 3;
  int sg = (t & 7) ^ (srow & 7);
  const unsigned short* agp = A + (size_t)(row0 + srow) * K + sg * 8;
  const unsigned short* bgp = Bm + (size_t)(col0 + srow) * K + sg * 8;
  int wr = w >> 1, wc = w & 1;
  f32x4 acc[4][4] = {};
  for (int k0 = 0; k0 < K; k0 += 64){
    __syncthreads();
#pragma unroll
    for (int i = 0; i < 4; i++){
      gload16(agp + (size_t)i * 32 * K + k0, sA + i * 4096 + w * 1024);
      gload16(bgp + (size_t)i * 32 * K + k0, sB + i * 4096 + w * 1024);
    }
    __syncthreads();
#pragma unroll
    for (int kk = 0; kk < 2; kk++){
      bf16x8 af[4], bfv[4];
#pragma unroll
      for (int m = 0; m < 4; m++){
        int row = wr * 64 + m * 16 + lr;
        int kg = kk * 4 + lg;
        af[m] = *(const bf16x8*)(sA + row * 128 + ((kg ^ (row & 7)) << 4));
      }
#pragma unroll
      for (int n = 0; n < 4; n++){
        int row = wc * 64 + n * 16 + lr;
        int kg = kk * 4 + lg;
        bfv[n] = *(const bf16x8*)(sB + row * 128 + ((kg ^ (row & 7)) << 4));
      }
#pragma unroll
      for (int m = 0; m < 4; m++)
#pragma unroll
        for (int n = 0; n < 4; n++)
          acc[m][n] = __builtin_amdgcn_mfma_f32_16x16x32_bf16(af[m], bfv[n], acc[m][n], 0, 0, 0);
    }
  }
#pragma unroll
  for (int m = 0; m < 4; m++)
#pragma unroll
    for (int n = 0; n < 4; n++)
#pragma unroll
      for (int r = 0; r < 4; r++){
        int rr = row0 + wr * 64 + m * 16 + lg * 4 + r;
        int cc = col0 + wc * 64 + n * 16 + lr;
        storeC(C, (size_t)rr * N + cc, acc[m][n][r]);
      }
}

// ---------------- flash attention fwd ----------------
// Q:[B*S,2048] roped, Kb:[B*S,512] roped, Vt:[B*4*128,S], O:[B*S,2048] bf16
__global__ __launch_bounds__(256, 2) void attn_fwd(const unsigned short* __restrict__ Q,
                                                   const unsigned short* __restrict__ Kb,
                                                   const unsigned short* __restrict__ Vt,
                                                   unsigned short* __restrict__ O){
  extern __shared__ char smem[];  // sK 16KB | sV 16KB | P: 4 x 4608B
  char* sK = smem; char* sV = smem + 16384;
  const float SOFT_C = 0.088388347648318447f * 1.4426950408889634f; // scale*log2(e)
  int bid = blockIdx.x;
  int qb = bid & 15, h = (bid >> 4) & 15, b = bid >> 8;
  int kvh = h >> 2;
  int t = threadIdx.x, w = t >> 6, l = t & 63;
  int lr = l & 15, lg = l >> 4;
  int q0 = qb * 128;
  char* sP = smem + 32768 + w * 4608;  // [32][72] bf16 rows (144B, 16B aligned)

  // Q fragments in registers (A-operand layout)
  bf16x8 qf[2][4];
  const unsigned short* qbase = Q + ((size_t)(b * S_LEN + q0 + w * 32)) * LDQ + h * HD;
#pragma unroll
  for (int m = 0; m < 2; m++)
#pragma unroll
    for (int kc = 0; kc < 4; kc++)
      qf[m][kc] = *(const bf16x8*)(qbase + (size_t)(m * 16 + lr) * LDQ + kc * 32 + lg * 8);

  f32x4 o_acc[2][8] = {};
  float m_run[2][4], l_run[2][4];
#pragma unroll
  for (int m = 0; m < 2; m++)
#pragma unroll
    for (int r = 0; r < 4; r++){ m_run[m][r] = -1e30f; l_run[m][r] = 0.f; }

  // staging coords. K tile [64][128] (rows=kv, ld=512); per inst 16 rows
  int k_srow = t >> 4;
  int k_g1 = t & 15;
  int k_g = (k_g1 & 8) | ((k_g1 ^ (k_srow & 7)) & 7);
  const unsigned short* kgp = Kb + (size_t)b * S_LEN * LDKV + kvh * HD + (size_t)k_srow * LDKV + k_g * 8;
  // Vt tile [128][64] (rows=d, ld=S); per inst 32 rows
  int v_srow = t >> 3;
  int v_g = (t & 7) ^ (v_srow & 7);
  const unsigned short* vgp = Vt + ((size_t)((b * N_KVH + kvh) * HD + v_srow)) * S_LEN + v_g * 8;

  int ntiles = 2 * (qb + 1);
  const int qrow_base = q0 + w * 32;
  for (int tix = 0; tix < ntiles; tix++){
    int k0 = tix * 64;
    __syncthreads();
#pragma unroll
    for (int i = 0; i < 4; i++)
      gload16(kgp + (size_t)(k0 + i * 16) * LDKV, sK + i * 4096 + w * 1024);
#pragma unroll
    for (int i = 0; i < 4; i++)
      gload16(vgp + (size_t)i * 32 * S_LEN + k0, sV + i * 4096 + w * 1024);
    __syncthreads();

    if (k0 <= qrow_base + 31){
      // ---- QK^T ----
      f32x4 sc[2][4] = {};
#pragma unroll
      for (int kc = 0; kc < 4; kc++){
        bf16x8 kf[4];
#pragma unroll
        for (int n = 0; n < 4; n++){
          int row = n * 16 + lr;
          int kg = kc * 4 + lg;                 // 0..15
          int pg = (kg & 8) | ((kg ^ (row & 7)) & 7);
          kf[n] = *(const bf16x8*)(sK + row * 256 + pg * 16);
        }
#pragma unroll
        for (int m = 0; m < 2; m++)
#pragma unroll
          for (int n = 0; n < 4; n++)
            sc[m][n] = __builtin_amdgcn_mfma_f32_16x16x32_bf16(qf[m][kc], kf[n], sc[m][n], 0, 0, 0);
      }
      // ---- causal mask (raw scores) ----
      if (k0 + 63 > qrow_base){
#pragma unroll
        for (int m = 0; m < 2; m++)
#pragma unroll
          for (int n = 0; n < 4; n++)
#pragma unroll
            for (int r = 0; r < 4; r++){
              int qr = qrow_base + m * 16 + lg * 4 + r;
              int kv = k0 + n * 16 + lr;
              if (kv > qr) sc[m][n][r] = -1e30f;
            }
      }
      // ---- online softmax ----
      float rescale[2][4];
#pragma unroll
      for (int m = 0; m < 2; m++)
#pragma unroll
        for (int r = 0; r < 4; r++){
          float v = fmaxf(fmaxf(sc[m][0][r], sc[m][1][r]), fmaxf(sc[m][2][r], sc[m][3][r]));
          v = red16max(v);
          float nm = fmaxf(m_run[m][r], v);
          rescale[m][r] = exp2f((m_run[m][r] - nm) * SOFT_C);
          m_run[m][r] = nm;
        }
#pragma unroll
      for (int m = 0; m < 2; m++){
        float ls[4] = {0.f, 0.f, 0.f, 0.f};
#pragma unroll
        for (int n = 0; n < 4; n++)
#pragma unroll
          for (int r = 0; r < 4; r++){
            float p = exp2f((sc[m][n][r] - m_run[m][r]) * SOFT_C);
            ls[r] += p;
            *(unsigned short*)(sP + (m * 16 + lg * 4 + r) * 144 + (n * 16 + lr) * 2) = f2bf(p);
          }
#pragma unroll
        for (int r = 0; r < 4; r++){
          float tot = red16sum(ls[r]);
          l_run[m][r] = l_run[m][r] * rescale[m][r] + tot;
        }
      }
#pragma unroll
      for (int m = 0; m < 2; m++)
#pragma unroll
        for (int nf = 0; nf < 8; nf++)
#pragma unroll
          for (int r = 0; r < 4; r++)
            o_acc[m][nf][r] *= rescale[m][r];
      // ---- PV ----
      bf16x8 pa[2][2];
#pragma unroll
      for (int m = 0; m < 2; m++)
#pragma unroll
        for (int kk = 0; kk < 2; kk++)
          pa[m][kk] = *(const bf16x8*)(sP + (m * 16 + lr) * 144 + kk * 64 + lg * 16);
#pragma unroll
      for (int kk = 0; kk < 2; kk++)
#pragma unroll
        for (int nf = 0; nf < 8; nf++){
          int row = nf * 16 + lr;
          int kg = kk * 4 + lg;                 // 0..7
          bf16x8 vb = *(const bf16x8*)(sV + row * 128 + ((kg ^ (row & 7)) << 4));
          o_acc[0][nf] = __builtin_amdgcn_mfma_f32_16x16x32_bf16(pa[0][kk], vb, o_acc[0][nf], 0, 0, 0);
          o_acc[1][nf] = __builtin_amdgcn_mfma_f32_16x16x32_bf16(pa[1][kk], vb, o_acc[1][nf], 0, 0, 0);
        }
    }
  }
  // ---- epilogue ----
  unsigned short* ob = O + ((size_t)(b * S_LEN + q0 + w * 32)) * LDQ + h * HD;
#pragma unroll
  for (int m = 0; m < 2; m++){
    float inv[4];
#pragma unroll
    for (int r = 0; r < 4; r++) inv[r] = 1.0f / l_run[m][r];
#pragma unroll
    for (int nf = 0; nf < 8; nf++)
#pragma unroll
      for (int r = 0; r < 4; r++)
        ob[(size_t)(m * 16 + lg * 4 + r) * LDQ + nf * 16 + lr] = f2bf(o_acc[m][nf][r] * inv[r]);
  }
}

extern "C" void kernel_launch(void* const* d_in, const int* in_sizes, int n_in,
                              void* d_out, int out_size, void* d_ws, size_t ws_size,
                              hipStream_t stream) {
  const float* x  = (const float*)d_in[0];
  const float* fc = (const float*)d_in[1];
  const float* wq = (const float*)d_in[2];
  const float* wk = (const float*)d_in[3];
  const float* wv = (const float*)d_in[4];
  const float* wo = (const float*)d_in[5];
  float* out = (float*)d_out;

  char* ws = (char*)d_ws;
  unsigned short* xb  = (unsigned short*)(ws);                 // 16 MB  x bf16 [4096,2048]
  unsigned short* wqb = (unsigned short*)(ws + 16777216);      // 8 MB
  unsigned short* wkb = (unsigned short*)(ws + 25165824);      // 2 MB
  unsigned short* wvb = (unsigned short*)(ws + 27262976);      // 2 MB
  unsigned short* wob = (unsigned short*)(ws + 29360128);      // 8 MB
  unsigned short* qb_ = (unsigned short*)(ws + 37748736);      // 16 MB  [4096,2048]
  unsigned short* kb_ = (unsigned short*)(ws + 54525952);      // 4 MB   [4096,512]
  unsigned short* vb_ = (unsigned short*)(ws + 58720256);      // 4 MB   [4096,512]
  unsigned short* vtb = (unsigned short*)(ws + 62914560);      // 4 MB   [1024,2048]
  unsigned short* ab_ = (unsigned short*)(ws + 67108864);      // 16 MB  attn out bf16

  // casts to bf16
  cast_bf16<<<4096, 256, 0, stream>>>(x,  xb,  1048576);
  cast_bf16<<<2048, 256, 0, stream>>>(wq, wqb, 524288);
  cast_bf16<<<512,  256, 0, stream>>>(wk, wkb, 131072);
  cast_bf16<<<512,  256, 0, stream>>>(wv, wvb, 131072);
  cast_bf16<<<2048, 256, 0, stream>>>(wo, wob, 524288);

  // projections
  gemm_nt<unsigned short><<<512, 256, 32768, stream>>>(xb, wqb, qb_, 4096, 2048, 2048, 16);
  gemm_nt<unsigned short><<<128, 256, 32768, stream>>>(xb, wkb, kb_, 4096, 512,  2048, 4);
  gemm_nt<unsigned short><<<128, 256, 32768, stream>>>(xb, wvb, vb_, 4096, 512,  2048, 4);

  // RoPE q, k
  rope_kernel<<<4096, 256, 0, stream>>>(qb_, fc, 11, 1048576);
  rope_kernel<<<1024, 256, 0, stream>>>(kb_, fc, 9,  262144);

  // V transpose -> [b,kvh,d,s]
  transpose_v<<<dim3(128, 16), 256, 0, stream>>>(vb_, vtb);

  // attention
  attn_fwd<<<512, 256, 51200, stream>>>(qb_, kb_, vtb, ab_);

  // output projection -> fp32 d_out
  gemm_nt<float><<<512, 256, 32768, stream>>>(ab_, wob, out, 4096, 2048, 2048, 16);
}

// Round 2
// 272.182 us; speedup vs baseline: 1.2249x; 1.2249x over previous
//
#include <hip/hip_runtime.h>

#define S_LEN 2048
#define N_B 2
#define N_H 16
#define N_KVH 4
#define HD 128
#define LDQ 2048   // N_H*HD
#define LDKV 512   // N_KVH*HD

typedef __bf16 bf16x8 __attribute__((ext_vector_type(8)));
typedef float f32x4 __attribute__((ext_vector_type(4)));

__device__ __forceinline__ float bf2f(unsigned short u){
  unsigned int x = ((unsigned int)u) << 16; float f;
  __builtin_memcpy(&f, &x, 4); return f;
}
__device__ __forceinline__ unsigned short f2bf(float f){
  unsigned int x; __builtin_memcpy(&x, &f, 4);
  unsigned int r = x + 0x7fff + ((x >> 16) & 1);
  return (unsigned short)(r >> 16);
}
__device__ __forceinline__ unsigned int cvt_pk_bf16(float lo, float hi){
  unsigned int u;
  asm("v_cvt_pk_bf16_f32 %0, %1, %2" : "=v"(u) : "v"(lo), "v"(hi));
  return u;
}
__device__ __forceinline__ void gload16(const void* g, void* l){
  __builtin_amdgcn_global_load_lds((const __attribute__((address_space(1))) void*)g,
                                   (__attribute__((address_space(3))) void*)l, 16, 0, 0);
}

// ---------------- cast fp32 -> bf16, 8 elems/thread ----------------
__global__ void cast_bf16(const float* __restrict__ in, unsigned short* __restrict__ out, int n8){
  int i = blockIdx.x * 256 + threadIdx.x;
  if (i >= n8) return;
  const float4* p = (const float4*)in + (size_t)i * 2;
  float4 a = p[0], b = p[1];
  uint4 o;
  o.x = (unsigned)f2bf(a.x) | ((unsigned)f2bf(a.y) << 16);
  o.y = (unsigned)f2bf(a.z) | ((unsigned)f2bf(a.w) << 16);
  o.z = (unsigned)f2bf(b.x) | ((unsigned)f2bf(b.y) << 16);
  o.w = (unsigned)f2bf(b.z) | ((unsigned)f2bf(b.w) << 16);
  ((uint4*)out)[i] = o;
}

// ---------------- RoPE in-place on bf16 buffer ----------------
__global__ void rope_kernel(unsigned short* __restrict__ X, const float* __restrict__ FC,
                            int ld_log2, int n8){
  int i = blockIdx.x * 256 + threadIdx.x;
  if (i >= n8) return;
  int idx = i * 8;
  int col = idx & ((1 << ld_log2) - 1);
  int token = idx >> ld_log2;
  int s = token & (S_LEN - 1);
  int d = col & (HD - 1);
  uint4 v = *(const uint4*)(X + idx);
  unsigned short* pv = (unsigned short*)&v;
  const float4* f4 = (const float4*)FC + ((size_t)s * 64 + (d >> 1));
  uint4 ov; unsigned short* po = (unsigned short*)&ov;
#pragma unroll
  for (int p = 0; p < 4; p++){
    float4 f = f4[p];
    float e = bf2f(pv[2*p]), o = bf2f(pv[2*p+1]);
    po[2*p]   = f2bf(f.x * e + f.y * o);
    po[2*p+1] = f2bf(f.z * e + f.w * o);
  }
  *(uint4*)(X + idx) = ov;
}

// ---------------- transpose V [B*S,512] -> Vt [B*4*128, S] ----------------
__global__ void transpose_v(const unsigned short* __restrict__ V, unsigned short* __restrict__ Vt){
  __shared__ unsigned short tile[32][33];
  int t = threadIdx.x;
  int s0 = blockIdx.x * 32;   // token tile
  int c0 = blockIdx.y * 32;   // col tile within 512
  int r = t >> 3, cg = (t & 7) * 4;
  uint2 in2 = *(const uint2*)(V + (size_t)(s0 + r) * LDKV + c0 + cg);
  unsigned short* pi = (unsigned short*)&in2;
  tile[r][cg+0] = pi[0]; tile[r][cg+1] = pi[1]; tile[r][cg+2] = pi[2]; tile[r][cg+3] = pi[3];
  __syncthreads();
  int b = s0 >> 11, sl = s0 & (S_LEN - 1);
  int kvh = c0 >> 7, dd0 = c0 & (HD - 1);
  int dd = t >> 3, sg = (t & 7) * 4;
  uint2 o2; unsigned short* po = (unsigned short*)&o2;
  po[0] = tile[sg+0][dd]; po[1] = tile[sg+1][dd]; po[2] = tile[sg+2][dd]; po[3] = tile[sg+3][dd];
  *(uint2*)(Vt + (size_t)((b * N_KVH + kvh) * HD + dd0 + dd) * S_LEN + sl + sg) = o2;
}

// ---------------- NT GEMM: C[M,N] = A[M,K] * Bm[N,K]^T, bf16 in, fp32 acc ----------------
__device__ __forceinline__ void storeC(float* C, size_t idx, float v){ C[idx] = v; }
__device__ __forceinline__ void storeC(unsigned short* C, size_t idx, float v){ C[idx] = f2bf(v); }

template <typename OutT>
__global__ __launch_bounds__(256, 2) void gemm_nt(const unsigned short* __restrict__ A,
                                                  const unsigned short* __restrict__ Bm,
                                                  OutT* __restrict__ C,
                                                  int M, int N, int K, int nbn){
  extern __shared__ char smem[];           // sA 16KB | sB 16KB
  char* sA = smem; char* sB = smem + 16384;
  int bid = blockIdx.x;
  int bn = bid % nbn, bm = bid / nbn;
  int row0 = bm * 128, col0 = bn * 128;
  int t = threadIdx.x; int w = t >> 6, l = t & 63;
  int lr = l & 15, lg = l >> 4;
  int srow = t >> 3;
  int sg = (t & 7) ^ (srow & 7);
  const unsigned short* agp = A + (size_t)(row0 + srow) * K + sg * 8;
  const unsigned short* bgp = Bm + (size_t)(col0 + srow) * K + sg * 8;
  int wr = w >> 1, wc = w & 1;
  f32x4 acc[4][4] = {};
  for (int k0 = 0; k0 < K; k0 += 64){
    __syncthreads();
#pragma unroll
    for (int i = 0; i < 4; i++){
      gload16(agp + (size_t)i * 32 * K + k0, sA + i * 4096 + w * 1024);
      gload16(bgp + (size_t)i * 32 * K + k0, sB + i * 4096 + w * 1024);
    }
    __syncthreads();
#pragma unroll
    for (int kk = 0; kk < 2; kk++){
      bf16x8 af[4], bfv[4];
#pragma unroll
      for (int m = 0; m < 4; m++){
        int row = wr * 64 + m * 16 + lr;
        int kg = kk * 4 + lg;
        af[m] = *(const bf16x8*)(sA + row * 128 + ((kg ^ (row & 7)) << 4));
      }
#pragma unroll
      for (int n = 0; n < 4; n++){
        int row = wc * 64 + n * 16 + lr;
        int kg = kk * 4 + lg;
        bfv[n] = *(const bf16x8*)(sB + row * 128 + ((kg ^ (row & 7)) << 4));
      }
#pragma unroll
      for (int m = 0; m < 4; m++)
#pragma unroll
        for (int n = 0; n < 4; n++)
          acc[m][n] = __builtin_amdgcn_mfma_f32_16x16x32_bf16(af[m], bfv[n], acc[m][n], 0, 0, 0);
    }
  }
#pragma unroll
  for (int m = 0; m < 4; m++)
#pragma unroll
    for (int n = 0; n < 4; n++)
#pragma unroll
      for (int r = 0; r < 4; r++){
        int rr = row0 + wr * 64 + m * 16 + lg * 4 + r;
        int cc = col0 + wc * 64 + n * 16 + lr;
        storeC(C, (size_t)rr * N + cc, acc[m][n][r]);
      }
}

// ---------------- flash attention fwd (swapped QK^T, balanced causal pairs) ----------------
// Q:[B*S,2048] roped, Kb:[B*S,512] roped, Vt:[B*4*128, S], O:[B*S,2048] bf16
// grid 512 = b(2) x h(16) x pair(16). Block does q-tiles {pr, 31-pr} of 64 rows,
// 4 waves x 16 q-rows. Each block: exactly 33 kv-tiles of 64 -> zero tail.
__global__ __launch_bounds__(256, 2) void attn_fwd(const unsigned short* __restrict__ Q,
                                                   const unsigned short* __restrict__ Kb,
                                                   const unsigned short* __restrict__ Vt,
                                                   unsigned short* __restrict__ O){
  extern __shared__ char smem[];  // sK 16KB | sV 16KB
  char* sK = smem; char* sV = smem + 16384;
  const float SOFT_C = 0.088388347648318447f * 1.4426950408889634f; // scale*log2(e)
  int bid = blockIdx.x;
  int pr = bid & 15, h = (bid >> 4) & 15, b = bid >> 8;
  int kvh = h >> 2;
  int t = threadIdx.x, w = t >> 6, l = t & 63;
  int lr = l & 15, lg = l >> 4;

  // staging coords (constant across phases)
  int k_srow = t >> 4;
  int k_g1 = t & 15;
  int k_g = (k_g1 & 8) | ((k_g1 ^ (k_srow & 7)) & 7);
  const unsigned short* kgp = Kb + (size_t)b * S_LEN * LDKV + kvh * HD + (size_t)k_srow * LDKV + k_g * 8;
  int v_srow = t >> 3;
  int v_g = (t & 7) ^ (v_srow & 7);
  const unsigned short* vgp = Vt + ((size_t)((b * N_KVH + kvh) * HD + v_srow)) * S_LEN + v_g * 8;

  for (int phase = 0; phase < 2; phase++){
    int qt = phase ? (31 - pr) : pr;
    int qrow_base = qt * 64 + w * 16;
    int q_lane = qrow_base + lr;        // this lane's q-row
    // Q fragments (B-operand layout: [col=q][k=d])
    bf16x8 qf[4];
    const unsigned short* qbase = Q + ((size_t)(b * S_LEN + q_lane)) * LDQ + h * HD;
#pragma unroll
    for (int kc = 0; kc < 4; kc++)
      qf[kc] = *(const bf16x8*)(qbase + kc * 32 + lg * 8);

    f32x4 o_acc[8] = {};
    float m_run = -1e30f, l_run = 0.f;
    int ntiles = qt + 1;
    for (int tix = 0; tix < ntiles; tix++){
      int k0 = tix * 64;
      __syncthreads();
#pragma unroll
      for (int i = 0; i < 4; i++)
        gload16(kgp + (size_t)(k0 + i * 16) * LDKV, sK + i * 4096 + w * 1024);
#pragma unroll
      for (int i = 0; i < 4; i++)
        gload16(vgp + (size_t)i * 32 * S_LEN + k0, sV + i * 4096 + w * 1024);
      __syncthreads();

      // ---- QK^T (swapped): sc[n] = S^T tile, row=kv (n*16+lg*4+r), col=q (lr) ----
      f32x4 sc[4] = {};
#pragma unroll
      for (int kc = 0; kc < 4; kc++){
#pragma unroll
        for (int n = 0; n < 4; n++){
          int row = n * 16 + lr;
          int kg = kc * 4 + lg;
          int pg = (kg & 8) | ((kg ^ (row & 7)) & 7);
          bf16x8 kf = *(const bf16x8*)(sK + row * 256 + pg * 16);
          sc[n] = __builtin_amdgcn_mfma_f32_16x16x32_bf16(kf, qf[kc], sc[n], 0, 0, 0);
        }
      }
      // ---- causal mask on diagonal tile ----
      if (tix == ntiles - 1){
#pragma unroll
        for (int n = 0; n < 4; n++)
#pragma unroll
          for (int r = 0; r < 4; r++){
            int kv = k0 + n * 16 + lg * 4 + r;
            if (kv > q_lane) sc[n][r] = -1e30f;
          }
      }
      // ---- online softmax: all 16 values in-lane belong to q-row lr ----
      float tmax = sc[0][0];
#pragma unroll
      for (int n = 0; n < 4; n++)
#pragma unroll
        for (int r = 0; r < 4; r++) tmax = fmaxf(tmax, sc[n][r]);
      tmax = fmaxf(tmax, __shfl_xor(tmax, 16));
      tmax = fmaxf(tmax, __shfl_xor(tmax, 32));
      float nm = fmaxf(m_run, tmax);
      float rs = exp2f((m_run - nm) * SOFT_C);
      m_run = nm;
      float p[4][4];
      float lsum = 0.f;
#pragma unroll
      for (int n = 0; n < 4; n++)
#pragma unroll
        for (int r = 0; r < 4; r++){
          float pv = exp2f((sc[n][r] - nm) * SOFT_C);
          p[n][r] = pv;
          lsum += pv;
        }
      lsum += __shfl_xor(lsum, 16);
      lsum += __shfl_xor(lsum, 32);
      l_run = l_run * rs + lsum;
#pragma unroll
      for (int nf = 0; nf < 8; nf++)
#pragma unroll
        for (int r = 0; r < 4; r++) o_acc[nf][r] *= rs;

      // ---- pack P to bf16 pairs & redistribute to PV B-frags ----
      unsigned int wpk[4][2];
#pragma unroll
      for (int n = 0; n < 4; n++){
        wpk[n][0] = cvt_pk_bf16(p[n][0], p[n][1]);
        wpk[n][1] = cvt_pk_bf16(p[n][2], p[n][3]);
      }
      int srcbase = lr + ((l & 16) << 1);      // lr + 32*(lg&1)
      bf16x8 pb[2];
#pragma unroll
      for (int kk = 0; kk < 2; kk++){
        unsigned int pu[4];
#pragma unroll
        for (int jj = 0; jj < 4; jj++){
          int src = srcbase + ((jj & 2) << 3); // +16*(jj>>1)
          unsigned int rA = (unsigned int)__shfl((int)wpk[2*kk][jj & 1], src, 64);
          unsigned int rB = (unsigned int)__shfl((int)wpk[2*kk+1][jj & 1], src, 64);
          pu[jj] = (l & 32) ? rB : rA;
        }
        pb[kk] = *(bf16x8*)pu;
      }
      // ---- PV: O^T += V^T * P^T ----
#pragma unroll
      for (int kk = 0; kk < 2; kk++)
#pragma unroll
        for (int nf = 0; nf < 8; nf++){
          int row = nf * 16 + lr;
          int kg = kk * 4 + lg;
          bf16x8 va = *(const bf16x8*)(sV + row * 128 + ((kg ^ (row & 7)) << 4));
          o_acc[nf] = __builtin_amdgcn_mfma_f32_16x16x32_bf16(va, pb[kk], o_acc[nf], 0, 0, 0);
        }
    }
    // ---- epilogue: lane holds O^T col q=lr, rows d = nf*16+lg*4+r ----
    float inv = 1.0f / l_run;
    unsigned short* ob = O + ((size_t)(b * S_LEN + q_lane)) * LDQ + h * HD;
#pragma unroll
    for (int nf = 0; nf < 8; nf++){
      unsigned int u0 = cvt_pk_bf16(o_acc[nf][0] * inv, o_acc[nf][1] * inv);
      unsigned int u1 = cvt_pk_bf16(o_acc[nf][2] * inv, o_acc[nf][3] * inv);
      uint2 o2; o2.x = u0; o2.y = u1;
      *(uint2*)(ob + nf * 16 + lg * 4) = o2;
    }
  }
}

extern "C" void kernel_launch(void* const* d_in, const int* in_sizes, int n_in,
                              void* d_out, int out_size, void* d_ws, size_t ws_size,
                              hipStream_t stream) {
  const float* x  = (const float*)d_in[0];
  const float* fc = (const float*)d_in[1];
  const float* wq = (const float*)d_in[2];
  const float* wk = (const float*)d_in[3];
  const float* wv = (const float*)d_in[4];
  const float* wo = (const float*)d_in[5];
  float* out = (float*)d_out;

  char* ws = (char*)d_ws;
  unsigned short* xb  = (unsigned short*)(ws);                 // 16 MB  x bf16 [4096,2048]
  unsigned short* wqb = (unsigned short*)(ws + 16777216);      // 8 MB
  unsigned short* wkb = (unsigned short*)(ws + 25165824);      // 2 MB
  unsigned short* wvb = (unsigned short*)(ws + 27262976);      // 2 MB
  unsigned short* wob = (unsigned short*)(ws + 29360128);      // 8 MB
  unsigned short* qb_ = (unsigned short*)(ws + 37748736);      // 16 MB  [4096,2048]
  unsigned short* kb_ = (unsigned short*)(ws + 54525952);      // 4 MB   [4096,512]
  unsigned short* vb_ = (unsigned short*)(ws + 58720256);      // 4 MB   [4096,512]
  unsigned short* vtb = (unsigned short*)(ws + 62914560);      // 4 MB   [1024,2048]
  unsigned short* ab_ = (unsigned short*)(ws + 67108864);      // 16 MB  attn out bf16

  // casts to bf16
  cast_bf16<<<4096, 256, 0, stream>>>(x,  xb,  1048576);
  cast_bf16<<<2048, 256, 0, stream>>>(wq, wqb, 524288);
  cast_bf16<<<512,  256, 0, stream>>>(wk, wkb, 131072);
  cast_bf16<<<512,  256, 0, stream>>>(wv, wvb, 131072);
  cast_bf16<<<2048, 256, 0, stream>>>(wo, wob, 524288);

  // projections
  gemm_nt<unsigned short><<<512, 256, 32768, stream>>>(xb, wqb, qb_, 4096, 2048, 2048, 16);
  gemm_nt<unsigned short><<<128, 256, 32768, stream>>>(xb, wkb, kb_, 4096, 512,  2048, 4);
  gemm_nt<unsigned short><<<128, 256, 32768, stream>>>(xb, wvb, vb_, 4096, 512,  2048, 4);

  // RoPE q, k
  rope_kernel<<<4096, 256, 0, stream>>>(qb_, fc, 11, 1048576);
  rope_kernel<<<1024, 256, 0, stream>>>(kb_, fc, 9,  262144);

  // V transpose -> [b,kvh,d,s]
  transpose_v<<<dim3(128, 16), 256, 0, stream>>>(vb_, vtb);

  // attention (swapped-QK^T, balanced pairs)
  attn_fwd<<<512, 256, 32768, stream>>>(qb_, kb_, vtb, ab_);

  // output projection -> fp32 d_out
  gemm_nt<float><<<512, 256, 32768, stream>>>(ab_, wob, out, 4096, 2048, 2048, 16);
}

// Round 3
// 263.739 us; speedup vs baseline: 1.2641x; 1.0320x over previous
//
#include <hip/hip_runtime.h>

#define S_LEN 2048
#define N_B 2
#define N_H 16
#define N_KVH 4
#define HD 128
#define LDQ 2048   // N_H*HD
#define LDKV 512   // N_KVH*HD

typedef __bf16 bf16x8 __attribute__((ext_vector_type(8)));
typedef float f32x4 __attribute__((ext_vector_type(4)));

__device__ __forceinline__ float bf2f(unsigned short u){
  unsigned int x = ((unsigned int)u) << 16; float f;
  __builtin_memcpy(&f, &x, 4); return f;
}
__device__ __forceinline__ unsigned short f2bf(float f){
  unsigned int x; __builtin_memcpy(&x, &f, 4);
  unsigned int r = x + 0x7fff + ((x >> 16) & 1);
  return (unsigned short)(r >> 16);
}
__device__ __forceinline__ unsigned int cvt_pk_bf16(float lo, float hi){
  unsigned int u;
  asm("v_cvt_pk_bf16_f32 %0, %1, %2" : "=v"(u) : "v"(lo), "v"(hi));
  return u;
}
__device__ __forceinline__ void gload16(const void* g, void* l){
  __builtin_amdgcn_global_load_lds((const __attribute__((address_space(1))) void*)g,
                                   (__attribute__((address_space(3))) void*)l, 16, 0, 0);
}

// ---------------- cast fp32 -> bf16, 8 elems/thread ----------------
__global__ void cast_bf16(const float* __restrict__ in, unsigned short* __restrict__ out, int n8){
  int i = blockIdx.x * 256 + threadIdx.x;
  if (i >= n8) return;
  const float4* p = (const float4*)in + (size_t)i * 2;
  float4 a = p[0], b = p[1];
  uint4 o;
  o.x = (unsigned)f2bf(a.x) | ((unsigned)f2bf(a.y) << 16);
  o.y = (unsigned)f2bf(a.z) | ((unsigned)f2bf(a.w) << 16);
  o.z = (unsigned)f2bf(b.x) | ((unsigned)f2bf(b.y) << 16);
  o.w = (unsigned)f2bf(b.z) | ((unsigned)f2bf(b.w) << 16);
  ((uint4*)out)[i] = o;
}

// ---------------- RoPE in-place on bf16 buffer ----------------
__global__ void rope_kernel(unsigned short* __restrict__ X, const float* __restrict__ FC,
                            int ld_log2, int n8){
  int i = blockIdx.x * 256 + threadIdx.x;
  if (i >= n8) return;
  int idx = i * 8;
  int col = idx & ((1 << ld_log2) - 1);
  int token = idx >> ld_log2;
  int s = token & (S_LEN - 1);
  int d = col & (HD - 1);
  uint4 v = *(const uint4*)(X + idx);
  unsigned short* pv = (unsigned short*)&v;
  const float4* f4 = (const float4*)FC + ((size_t)s * 64 + (d >> 1));
  uint4 ov; unsigned short* po = (unsigned short*)&ov;
#pragma unroll
  for (int p = 0; p < 4; p++){
    float4 f = f4[p];
    float e = bf2f(pv[2*p]), o = bf2f(pv[2*p+1]);
    po[2*p]   = f2bf(f.x * e + f.y * o);
    po[2*p+1] = f2bf(f.z * e + f.w * o);
  }
  *(uint4*)(X + idx) = ov;
}

// ---------------- transpose V [B*S,512] -> Vt [B*4*128, S] ----------------
__global__ void transpose_v(const unsigned short* __restrict__ V, unsigned short* __restrict__ Vt){
  __shared__ unsigned short tile[32][33];
  int t = threadIdx.x;
  int s0 = blockIdx.x * 32;   // token tile
  int c0 = blockIdx.y * 32;   // col tile within 512
  int r = t >> 3, cg = (t & 7) * 4;
  uint2 in2 = *(const uint2*)(V + (size_t)(s0 + r) * LDKV + c0 + cg);
  unsigned short* pi = (unsigned short*)&in2;
  tile[r][cg+0] = pi[0]; tile[r][cg+1] = pi[1]; tile[r][cg+2] = pi[2]; tile[r][cg+3] = pi[3];
  __syncthreads();
  int b = s0 >> 11, sl = s0 & (S_LEN - 1);
  int kvh = c0 >> 7, dd0 = c0 & (HD - 1);
  int dd = t >> 3, sg = (t & 7) * 4;
  uint2 o2; unsigned short* po = (unsigned short*)&o2;
  po[0] = tile[sg+0][dd]; po[1] = tile[sg+1][dd]; po[2] = tile[sg+2][dd]; po[3] = tile[sg+3][dd];
  *(uint2*)(Vt + (size_t)((b * N_KVH + kvh) * HD + dd0 + dd) * S_LEN + sl + sg) = o2;
}

// ---------------- NT GEMM: C[M,N] = A[M,K] * Bm[N,K]^T, bf16 in, fp32 acc ----------------
__device__ __forceinline__ void storeC(float* C, size_t idx, float v){ C[idx] = v; }
__device__ __forceinline__ void storeC(unsigned short* C, size_t idx, float v){ C[idx] = f2bf(v); }

template <typename OutT>
__global__ __launch_bounds__(256, 2) void gemm_nt(const unsigned short* __restrict__ A,
                                                  const unsigned short* __restrict__ Bm,
                                                  OutT* __restrict__ C,
                                                  int M, int N, int K, int nbn){
  extern __shared__ char smem[];           // sA 16KB | sB 16KB
  char* sA = smem; char* sB = smem + 16384;
  int bid = blockIdx.x;
  int bn = bid % nbn, bm = bid / nbn;
  int row0 = bm * 128, col0 = bn * 128;
  int t = threadIdx.x; int w = t >> 6, l = t & 63;
  int lr = l & 15, lg = l >> 4;
  int srow = t >> 3;
  int sg = (t & 7) ^ (srow & 7);
  const unsigned short* agp = A + (size_t)(row0 + srow) * K + sg * 8;
  const unsigned short* bgp = Bm + (size_t)(col0 + srow) * K + sg * 8;
  int wr = w >> 1, wc = w & 1;
  f32x4 acc[4][4] = {};
  for (int k0 = 0; k0 < K; k0 += 64){
    __syncthreads();
#pragma unroll
    for (int i = 0; i < 4; i++){
      gload16(agp + (size_t)i * 32 * K + k0, sA + i * 4096 + w * 1024);
      gload16(bgp + (size_t)i * 32 * K + k0, sB + i * 4096 + w * 1024);
    }
    __syncthreads();
#pragma unroll
    for (int kk = 0; kk < 2; kk++){
      bf16x8 af[4], bfv[4];
#pragma unroll
      for (int m = 0; m < 4; m++){
        int row = wr * 64 + m * 16 + lr;
        int kg = kk * 4 + lg;
        af[m] = *(const bf16x8*)(sA + row * 128 + ((kg ^ (row & 7)) << 4));
      }
#pragma unroll
      for (int n = 0; n < 4; n++){
        int row = wc * 64 + n * 16 + lr;
        int kg = kk * 4 + lg;
        bfv[n] = *(const bf16x8*)(sB + row * 128 + ((kg ^ (row & 7)) << 4));
      }
#pragma unroll
      for (int m = 0; m < 4; m++)
#pragma unroll
        for (int n = 0; n < 4; n++)
          acc[m][n] = __builtin_amdgcn_mfma_f32_16x16x32_bf16(af[m], bfv[n], acc[m][n], 0, 0, 0);
    }
  }
#pragma unroll
  for (int m = 0; m < 4; m++)
#pragma unroll
    for (int n = 0; n < 4; n++)
#pragma unroll
      for (int r = 0; r < 4; r++){
        int rr = row0 + wr * 64 + m * 16 + lg * 4 + r;
        int cc = col0 + wc * 64 + n * 16 + lr;
        storeC(C, (size_t)rr * N + cc, acc[m][n][r]);
      }
}

// ---------------- flash attention fwd (swapped QK^T, dbuf staging, defer-max) ----------------
// Q:[B*S,2048] roped, Kb:[B*S,512] roped, Vt:[B*4*128, S], O:[B*S,2048] bf16
// grid 512 = b(2) x h(16) x pair(16). Block does q-tiles {pr, 31-pr} (33 kv-tiles total).
__global__ __launch_bounds__(256, 2) void attn_fwd(const unsigned short* __restrict__ Q,
                                                   const unsigned short* __restrict__ Kb,
                                                   const unsigned short* __restrict__ Vt,
                                                   unsigned short* __restrict__ O){
  extern __shared__ char smem[];  // 2 x (sK 16KB | sV 16KB) = 64KB
  const float SOFT_C = 0.088388347648318447f * 1.4426950408889634f; // scale*log2(e)
  const float THR_RAW = 62.0f;                                      // ~8 / SOFT_C
  int bid = blockIdx.x;
  int pr = bid & 15, h = (bid >> 4) & 15, b = bid >> 8;
  int kvh = h >> 2;
  int t = threadIdx.x, w = t >> 6, l = t & 63;
  int lr = l & 15, lg = l >> 4;

  // staging coords (constant across phases)
  int k_srow = t >> 4;
  int k_g1 = t & 15;
  int k_g = (k_g1 & 8) | ((k_g1 ^ (k_srow & 7)) & 7);
  const unsigned short* kgp = Kb + (size_t)b * S_LEN * LDKV + kvh * HD + (size_t)k_srow * LDKV + k_g * 8;
  int v_srow = t >> 3;
  int v_g = (t & 7) ^ (v_srow & 7);
  const unsigned short* vgp = Vt + ((size_t)((b * N_KVH + kvh) * HD + v_srow)) * S_LEN + v_g * 8;

  for (int phase = 0; phase < 2; phase++){
    int qt = phase ? (31 - pr) : pr;
    int qrow_base = qt * 64 + w * 16;
    int q_lane = qrow_base + lr;        // this lane's q-row
    // Q fragments (B-operand layout: [col=q][k=d])
    bf16x8 qf[4];
    const unsigned short* qbase = Q + ((size_t)(b * S_LEN + q_lane)) * LDQ + h * HD;
#pragma unroll
    for (int kc = 0; kc < 4; kc++)
      qf[kc] = *(const bf16x8*)(qbase + kc * 32 + lg * 8);

    f32x4 o_acc[8] = {};
    float m_run = -1e30f, l_run = 0.f;
    int ntiles = qt + 1;

    // prologue: stage tile 0 into buffer 0
    int cur = 0;
#pragma unroll
    for (int i = 0; i < 4; i++)
      gload16(kgp + (size_t)(i * 16) * LDKV, smem + i * 4096 + w * 1024);
#pragma unroll
    for (int i = 0; i < 4; i++)
      gload16(vgp + (size_t)i * 32 * S_LEN, smem + 16384 + i * 4096 + w * 1024);
    __syncthreads();   // drains vmcnt(0)

    for (int tix = 0; tix < ntiles; tix++){
      int k0 = tix * 64;
      char* sK = smem + (cur << 15);
      char* sV = sK + 16384;
      // issue next tile's stage into the other buffer (overlaps with compute)
      if (tix + 1 < ntiles){
        char* nK = smem + ((cur ^ 1) << 15);
        int nk0 = k0 + 64;
#pragma unroll
        for (int i = 0; i < 4; i++)
          gload16(kgp + (size_t)(nk0 + i * 16) * LDKV, nK + i * 4096 + w * 1024);
#pragma unroll
        for (int i = 0; i < 4; i++)
          gload16(vgp + (size_t)i * 32 * S_LEN + nk0, nK + 16384 + i * 4096 + w * 1024);
      }

      // ---- QK^T (swapped): sc[n] row=kv (n*16+lg*4+r), col=q (lr) ----
      f32x4 sc[4] = {};
      __builtin_amdgcn_s_setprio(1);
#pragma unroll
      for (int kc = 0; kc < 4; kc++){
#pragma unroll
        for (int n = 0; n < 4; n++){
          int row = n * 16 + lr;
          int kg = kc * 4 + lg;
          int pg = (kg & 8) | ((kg ^ (row & 7)) & 7);
          bf16x8 kf = *(const bf16x8*)(sK + row * 256 + pg * 16);
          sc[n] = __builtin_amdgcn_mfma_f32_16x16x32_bf16(kf, qf[kc], sc[n], 0, 0, 0);
        }
      }
      __builtin_amdgcn_s_setprio(0);
      // ---- causal mask on diagonal tile ----
      if (tix == ntiles - 1){
#pragma unroll
        for (int n = 0; n < 4; n++)
#pragma unroll
          for (int r = 0; r < 4; r++){
            int kv = k0 + n * 16 + lg * 4 + r;
            if (kv > q_lane) sc[n][r] = -1e30f;
          }
      }
      // ---- online softmax with defer-max ----
      float tmax = sc[0][0];
#pragma unroll
      for (int n = 0; n < 4; n++)
#pragma unroll
        for (int r = 0; r < 4; r++) tmax = fmaxf(tmax, sc[n][r]);
      tmax = fmaxf(tmax, __shfl_xor(tmax, 16));
      tmax = fmaxf(tmax, __shfl_xor(tmax, 32));
      if (!__all(tmax - m_run <= THR_RAW)){
        float nm = fmaxf(m_run, tmax);
        float rs = exp2f((m_run - nm) * SOFT_C);
        m_run = nm;
        l_run *= rs;
#pragma unroll
        for (int nf = 0; nf < 8; nf++)
#pragma unroll
          for (int r = 0; r < 4; r++) o_acc[nf][r] *= rs;
      }
      float p[4][4];
      float lsum = 0.f;
#pragma unroll
      for (int n = 0; n < 4; n++)
#pragma unroll
        for (int r = 0; r < 4; r++){
          float pv = exp2f((sc[n][r] - m_run) * SOFT_C);
          p[n][r] = pv;
          lsum += pv;
        }
      lsum += __shfl_xor(lsum, 16);
      lsum += __shfl_xor(lsum, 32);
      l_run += lsum;

      // ---- pack P to bf16 pairs & redistribute to PV B-frags ----
      unsigned int wpk[4][2];
#pragma unroll
      for (int n = 0; n < 4; n++){
        wpk[n][0] = cvt_pk_bf16(p[n][0], p[n][1]);
        wpk[n][1] = cvt_pk_bf16(p[n][2], p[n][3]);
      }
      int srcbase = lr + ((l & 16) << 1);      // lr + 32*(lg&1)
      bf16x8 pb[2];
#pragma unroll
      for (int kk = 0; kk < 2; kk++){
        unsigned int pu[4];
#pragma unroll
        for (int jj = 0; jj < 4; jj++){
          int src = srcbase + ((jj & 2) << 3); // +16*(jj>>1)
          unsigned int rA = (unsigned int)__shfl((int)wpk[2*kk][jj & 1], src, 64);
          unsigned int rB = (unsigned int)__shfl((int)wpk[2*kk+1][jj & 1], src, 64);
          pu[jj] = (l & 32) ? rB : rA;
        }
        pb[kk] = *(bf16x8*)pu;
      }
      // ---- PV: O^T += V^T * P^T ----
      __builtin_amdgcn_s_setprio(1);
#pragma unroll
      for (int kk = 0; kk < 2; kk++)
#pragma unroll
        for (int nf = 0; nf < 8; nf++){
          int row = nf * 16 + lr;
          int kg = kk * 4 + lg;
          bf16x8 va = *(const bf16x8*)(sV + row * 128 + ((kg ^ (row & 7)) << 4));
          o_acc[nf] = __builtin_amdgcn_mfma_f32_16x16x32_bf16(va, pb[kk], o_acc[nf], 0, 0, 0);
        }
      __builtin_amdgcn_s_setprio(0);
      __syncthreads();   // next buffer staged + all reads of cur done
      cur ^= 1;
    }
    // ---- epilogue: lane holds O^T col q=lr, rows d = nf*16+lg*4+r ----
    float inv = 1.0f / l_run;
    unsigned short* ob = O + ((size_t)(b * S_LEN + q_lane)) * LDQ + h * HD;
#pragma unroll
    for (int nf = 0; nf < 8; nf++){
      unsigned int u0 = cvt_pk_bf16(o_acc[nf][0] * inv, o_acc[nf][1] * inv);
      unsigned int u1 = cvt_pk_bf16(o_acc[nf][2] * inv, o_acc[nf][3] * inv);
      uint2 o2; o2.x = u0; o2.y = u1;
      *(uint2*)(ob + nf * 16 + lg * 4) = o2;
    }
  }
}

extern "C" void kernel_launch(void* const* d_in, const int* in_sizes, int n_in,
                              void* d_out, int out_size, void* d_ws, size_t ws_size,
                              hipStream_t stream) {
  const float* x  = (const float*)d_in[0];
  const float* fc = (const float*)d_in[1];
  const float* wq = (const float*)d_in[2];
  const float* wk = (const float*)d_in[3];
  const float* wv = (const float*)d_in[4];
  const float* wo = (const float*)d_in[5];
  float* out = (float*)d_out;

  char* ws = (char*)d_ws;
  unsigned short* xb  = (unsigned short*)(ws);                 // 16 MB  x bf16 [4096,2048]
  unsigned short* wqb = (unsigned short*)(ws + 16777216);      // 8 MB
  unsigned short* wkb = (unsigned short*)(ws + 25165824);      // 2 MB
  unsigned short* wvb = (unsigned short*)(ws + 27262976);      // 2 MB
  unsigned short* wob = (unsigned short*)(ws + 29360128);      // 8 MB
  unsigned short* qb_ = (unsigned short*)(ws + 37748736);      // 16 MB  [4096,2048]
  unsigned short* kb_ = (unsigned short*)(ws + 54525952);      // 4 MB   [4096,512]
  unsigned short* vb_ = (unsigned short*)(ws + 58720256);      // 4 MB   [4096,512]
  unsigned short* vtb = (unsigned short*)(ws + 62914560);      // 4 MB   [1024,2048]
  unsigned short* ab_ = (unsigned short*)(ws + 67108864);      // 16 MB  attn out bf16

  // casts to bf16
  cast_bf16<<<4096, 256, 0, stream>>>(x,  xb,  1048576);
  cast_bf16<<<2048, 256, 0, stream>>>(wq, wqb, 524288);
  cast_bf16<<<512,  256, 0, stream>>>(wk, wkb, 131072);
  cast_bf16<<<512,  256, 0, stream>>>(wv, wvb, 131072);
  cast_bf16<<<2048, 256, 0, stream>>>(wo, wob, 524288);

  // projections
  gemm_nt<unsigned short><<<512, 256, 32768, stream>>>(xb, wqb, qb_, 4096, 2048, 2048, 16);
  gemm_nt<unsigned short><<<128, 256, 32768, stream>>>(xb, wkb, kb_, 4096, 512,  2048, 4);
  gemm_nt<unsigned short><<<128, 256, 32768, stream>>>(xb, wvb, vb_, 4096, 512,  2048, 4);

  // RoPE q, k
  rope_kernel<<<4096, 256, 0, stream>>>(qb_, fc, 11, 1048576);
  rope_kernel<<<1024, 256, 0, stream>>>(kb_, fc, 9,  262144);

  // V transpose -> [b,kvh,d,s]
  transpose_v<<<dim3(128, 16), 256, 0, stream>>>(vb_, vtb);

  // attention (swapped-QK^T, dbuf, defer-max, setprio)
  attn_fwd<<<512, 256, 65536, stream>>>(qb_, kb_, vtb, ab_);

  // output projection -> fp32 d_out
  gemm_nt<float><<<512, 256, 32768, stream>>>(ab_, wob, out, 4096, 2048, 2048, 16);
}